// Round 10
// baseline (211.266 us; speedup 1.0000x reference)
//
#include <hip/hip_runtime.h>

// PointNetRot9d. Round 10: A-operand LDS staging removed (both MFMA kernels).
//  - conv3: af frags loaded directly from w3h (L2-hot, one-time per block):
//    -32KB LDS (68->36), -1 barrier, -8-iter staging loop. dbuf+prefetch kept.
//  - conv12: af frags loaded directly from w2 as FP32 + in-register cvt
//    (same RNE quantization point); w2h removed from the whole pipeline,
//    k_prep shrinks to w3-cvt + x-moments (192 blocks).
//  - Everything else identical to r9 (passing, absmax 0.0137): closed-form
//    BN1, transposed fp16 y2t/h2t, swizzled pure-copy B staging, dbuf conv3,
//    pooled fused into fc1, stats on raw acc with bias folded at the end.

#define NPT 2048
#define C1 64
#define C2 128
#define EPSV 1e-5f

typedef __attribute__((ext_vector_type(8))) _Float16 half8;
typedef __attribute__((ext_vector_type(4))) float floatx4;

// ---- workspace layout (float-slot offsets) ----
#define OFF_Y2T   0               // 32*2048*128 halves = 4194304 slots
#define OFF_H2T   4194304         // 32*2048*128 halves = 4194304 slots
#define OFF_Z     8388608         // zeroed region start
#define OFF_XS    (OFF_Z)         // 16: Sx[3], Sxx diag[3], Sxx off[3]
#define OFF_SUM2  (OFF_Z+16)
#define OFF_SQ2   (OFF_Z+144)
#define OFF_SUM3  (OFF_Z+272)
#define OFF_SQ3   (OFF_Z+1296)
#define OFF_F1R   (OFF_Z+2320)    // 32*512
#define OFF_F2R   (OFF_Z+18704)   // 32*256
#define ZN        26896
#define OFF_MX    (OFF_Z+26896)   // 2 ns-slots * 32*1024
#define OFF_MN    (OFF_MX+65536)
#define OFF_W3H   (OFF_MN+65536)  // 131072 halves = 65536 slots
#define WS_FLOATS (OFF_W3H+65536) // 8,546,064 floats = 34.2 MB

static __device__ inline unsigned short f16r(float f) {
  _Float16 h = (_Float16)f;
  return __builtin_bit_cast(unsigned short, h);
}
static __device__ inline float h2f(unsigned short u) {
  return (float)__builtin_bit_cast(_Float16, u);
}
// LDS staging swizzle (bijection on n per cb): conflict-free b128 write+read.
static __device__ inline int SW(int n, int cb) { return n ^ (((n >> 3) ^ cb) & 7); }

// k_prep: blocks [0,128) cvt w3 -> fp16; blocks [128,192) x moments.
__global__ __launch_bounds__(256) void k_prep(const float* __restrict__ w3,
    unsigned short* __restrict__ w3h, const float* __restrict__ x,
    float* __restrict__ xs)
{
  int bi = blockIdx.x;
  int t = threadIdx.x;
  if (bi < 128) {
    int idx4 = bi * 256 + t;                   // 32768 f4
    float4 v = ((const float4*)w3)[idx4];
    ushort4 o;
    o.x = f16r(v.x); o.y = f16r(v.y); o.z = f16r(v.z); o.w = f16r(v.w);
    ((ushort4*)w3h)[idx4] = o;
    return;
  }
  int idx4 = (bi - 128) * 256 + t;             // 16384 f4 = [32 b][512 n4]
  int n4 = idx4 & 511, b = idx4 >> 9;
  const float4* xr = (const float4*)(x + (size_t)b * 3 * NPT);
  float4 x0 = xr[n4], x1 = xr[512 + n4], x2 = xr[1024 + n4];
  float v[9];
  v[0] = x0.x + x0.y + x0.z + x0.w;
  v[1] = x1.x + x1.y + x1.z + x1.w;
  v[2] = x2.x + x2.y + x2.z + x2.w;
  v[3] = x0.x*x0.x + x0.y*x0.y + x0.z*x0.z + x0.w*x0.w;
  v[4] = x1.x*x1.x + x1.y*x1.y + x1.z*x1.z + x1.w*x1.w;
  v[5] = x2.x*x2.x + x2.y*x2.y + x2.z*x2.z + x2.w*x2.w;
  v[6] = x0.x*x1.x + x0.y*x1.y + x0.z*x1.z + x0.w*x1.w;
  v[7] = x0.x*x2.x + x0.y*x2.y + x0.z*x2.z + x0.w*x2.w;
  v[8] = x1.x*x2.x + x1.y*x2.y + x1.z*x2.z + x1.w*x2.w;
  #pragma unroll
  for (int k = 0; k < 9; ++k)
    for (int off = 32; off; off >>= 1) v[k] += __shfl_down(v[k], off);
  __shared__ float red[4][9];
  int lane = t & 63, wv = t >> 6;
  if (!lane)
    #pragma unroll
    for (int k = 0; k < 9; ++k) red[wv][k] = v[k];
  __syncthreads();
  if (t < 9)
    atomicAdd(&xs[t], red[0][t] + red[1][t] + red[2][t] + red[3][t]);
}

// k_conv12: fused conv1(+BN1 closed form +relu, in-register) -> conv2 MFMA.
// A-frags direct from w2 (f32, in-register cvt). Block = (b, 64-n) x 128 o.
__global__ __launch_bounds__(256, 4) void k_conv12(const float* __restrict__ x,
    const float* __restrict__ w1, const float* __restrict__ b1,
    const float* __restrict__ g1, const float* __restrict__ be1,
    const float* __restrict__ xs,
    const float* __restrict__ w2, const float* __restrict__ b2,
    unsigned short* __restrict__ y2t, float* __restrict__ sum2, float* __restrict__ sq2)
{
  __shared__ unsigned short h1s[8 * 64 * 8];    // 8 KB
  __shared__ float wc[64][4];
  __shared__ float sred[2][128][2];
  int t = threadIdx.x;
  int bi = blockIdx.x;                 // 1024 = 32 b x 32 ns
  int b = bi >> 5, ns = bi & 31;
  int n0 = ns * 64;
  int w = t >> 6, lane = t & 63;
  int ow = w & 1, nw = w >> 1;
  int quad = lane >> 4, l15 = lane & 15;

  // A-frags: direct global f32 load + cvt (issued before barrier; L2-hot)
  half8 af[4][2];
  #pragma unroll
  for (int ti = 0; ti < 4; ++ti)
    #pragma unroll
    for (int s = 0; s < 2; ++s) {
      int cb = s * 4 + quad;
      int o = ow * 64 + ti * 16 + l15;
      const float* wrow = w2 + o * 64 + cb * 8;
      float4 f0 = *(const float4*)(wrow);
      float4 f1 = *(const float4*)(wrow + 4);
      half8 h;
      h[0] = (_Float16)f0.x; h[1] = (_Float16)f0.y;
      h[2] = (_Float16)f0.z; h[3] = (_Float16)f0.w;
      h[4] = (_Float16)f1.x; h[5] = (_Float16)f1.y;
      h[6] = (_Float16)f1.z; h[7] = (_Float16)f1.w;
      af[ti][s] = h;
    }

  // BN1 closed form -> folded conv1 coeffs
  if (t < 64) {
    float w0 = w1[t*3], w1_ = w1[t*3+1], w2_ = w1[t*3+2], bb = b1[t];
    const float invN = 1.f / 65536.f;
    float wsx = (w0*xs[0] + w1_*xs[1] + w2_*xs[2]) * invN;
    float mean = wsx + bb;
    float Ey2 = (w0*w0*xs[3] + w1_*w1_*xs[4] + w2_*w2_*xs[5]
               + 2.f*(w0*w1_*xs[6] + w0*w2_*xs[7] + w1_*w2_*xs[8])) * invN
               + 2.f*bb*wsx + bb*bb;
    float var = Ey2 - mean*mean;
    float a = g1[t] * rsqrtf(var + EPSV);
    wc[t][0] = a*w0; wc[t][1] = a*w1_; wc[t][2] = a*w2_;
    wc[t][3] = be1[t] + a*(bb - mean);
  }
  __syncthreads();                     // wc ready

  // compute h1 = relu(wc . x) for 8c x 2n per thread; pack to swizzled LDS
  {
    int cg = t >> 5, ng = t & 31;      // 8 c-groups x 32 n-pairs
    int c0 = cg * 8, nn = ng * 2;
    const float* xb = x + (size_t)b * 3 * NPT + n0 + nn;
    float2 xv0 = *(const float2*)(xb);
    float2 xv1 = *(const float2*)(xb + NPT);
    float2 xv2 = *(const float2*)(xb + 2 * NPT);
    uint4 p0, p1;
    unsigned* a0 = (unsigned*)&p0;
    unsigned* a1 = (unsigned*)&p1;
    #pragma unroll
    for (int j = 0; j < 4; ++j) {
      int c = c0 + j * 2;
      float hA0 = fmaxf(fmaf(wc[c][0], xv0.x, fmaf(wc[c][1], xv1.x, fmaf(wc[c][2], xv2.x, wc[c][3]))), 0.f);
      float hA1 = fmaxf(fmaf(wc[c][0], xv0.y, fmaf(wc[c][1], xv1.y, fmaf(wc[c][2], xv2.y, wc[c][3]))), 0.f);
      float hB0 = fmaxf(fmaf(wc[c+1][0], xv0.x, fmaf(wc[c+1][1], xv1.x, fmaf(wc[c+1][2], xv2.x, wc[c+1][3]))), 0.f);
      float hB1 = fmaxf(fmaf(wc[c+1][0], xv0.y, fmaf(wc[c+1][1], xv1.y, fmaf(wc[c+1][2], xv2.y, wc[c+1][3]))), 0.f);
      a0[j] = (unsigned)f16r(hA0) | ((unsigned)f16r(hB0) << 16);
      a1[j] = (unsigned)f16r(hA1) | ((unsigned)f16r(hB1) << 16);
    }
    *(uint4*)&h1s[(cg * 64 + SW(nn, cg)) * 8] = p0;
    *(uint4*)&h1s[(cg * 64 + SW(nn + 1, cg)) * 8] = p1;
  }
  __syncthreads();

  float breg[4][4];
  #pragma unroll
  for (int ti = 0; ti < 4; ++ti)
    #pragma unroll
    for (int r = 0; r < 4; ++r)
      breg[ti][r] = b2[ow * 64 + ti * 16 + quad * 4 + r];

  floatx4 acc[4][2];
  #pragma unroll
  for (int ti = 0; ti < 4; ++ti)
    #pragma unroll
    for (int nt = 0; nt < 2; ++nt) acc[ti][nt] = (floatx4){0.f, 0.f, 0.f, 0.f};
  #pragma unroll
  for (int s = 0; s < 2; ++s) {
    int cb = s * 4 + quad;
    half8 bf[2];
    #pragma unroll
    for (int nt = 0; nt < 2; ++nt) {
      int n = nw * 32 + nt * 16 + l15;
      bf[nt] = *(const half8*)&h1s[(cb * 64 + SW(n, cb)) * 8];
    }
    #pragma unroll
    for (int ti = 0; ti < 4; ++ti) {
      acc[ti][0] = __builtin_amdgcn_mfma_f32_16x16x32_f16(af[ti][s], bf[0], acc[ti][0], 0, 0, 0);
      acc[ti][1] = __builtin_amdgcn_mfma_f32_16x16x32_f16(af[ti][s], bf[1], acc[ti][1], 0, 0, 0);
    }
  }

  // epilogue: y2t[b][n][c] = fp16(acc + b2) via 8B stores; exact fp32 stats
  float sm[4][4], sq[4][4];
  #pragma unroll
  for (int ti = 0; ti < 4; ++ti)
    #pragma unroll
    for (int r = 0; r < 4; ++r) { sm[ti][r] = 0.f; sq[ti][r] = 0.f; }
  #pragma unroll
  for (int ti = 0; ti < 4; ++ti) {
    int o = ow * 64 + ti * 16 + quad * 4;
    #pragma unroll
    for (int nt = 0; nt < 2; ++nt) {
      int n = n0 + nw * 32 + nt * 16 + l15;
      float v0 = acc[ti][nt][0] + breg[ti][0];
      float v1 = acc[ti][nt][1] + breg[ti][1];
      float v2 = acc[ti][nt][2] + breg[ti][2];
      float v3 = acc[ti][nt][3] + breg[ti][3];
      ushort4 st;
      st.x = f16r(v0); st.y = f16r(v1); st.z = f16r(v2); st.w = f16r(v3);
      *(ushort4*)(y2t + ((size_t)b * NPT + n) * C2 + o) = st;
      sm[ti][0] += v0; sq[ti][0] = fmaf(v0, v0, sq[ti][0]);
      sm[ti][1] += v1; sq[ti][1] = fmaf(v1, v1, sq[ti][1]);
      sm[ti][2] += v2; sq[ti][2] = fmaf(v2, v2, sq[ti][2]);
      sm[ti][3] += v3; sq[ti][3] = fmaf(v3, v3, sq[ti][3]);
    }
  }
  #pragma unroll
  for (int ti = 0; ti < 4; ++ti)
    #pragma unroll
    for (int r = 0; r < 4; ++r) {
      #pragma unroll
      for (int m = 1; m < 16; m <<= 1) {
        sm[ti][r] += __shfl_xor(sm[ti][r], m, 16);
        sq[ti][r] += __shfl_xor(sq[ti][r], m, 16);
      }
    }
  if (l15 == 0) {
    #pragma unroll
    for (int ti = 0; ti < 4; ++ti)
      #pragma unroll
      for (int r = 0; r < 4; ++r) {
        int oloc = ow * 64 + ti * 16 + quad * 4 + r;
        sred[nw][oloc][0] = sm[ti][r];
        sred[nw][oloc][1] = sq[ti][r];
      }
  }
  __syncthreads();
  if (t < 128) {
    atomicAdd(&sum2[t], sred[0][t][0] + sred[1][t][0]);
    atomicAdd(&sq2[t],  sred[0][t][1] + sred[1][t][1]);
  }
}

// BN2+relu elementwise (linear, same layout): y2t -> h2t, fp32 BN math.
__global__ __launch_bounds__(256) void k_bnrelu2(const unsigned short* __restrict__ y2t,
    const float* __restrict__ sum2, const float* __restrict__ sq2,
    const float* __restrict__ g2, const float* __restrict__ be2,
    unsigned short* __restrict__ h2t)
{
  __shared__ float bn[128][2];
  int t = threadIdx.x;
  if (t < 128) {
    float m = sum2[t] * (1.f / 65536.f);
    float v = fmaf(-m, m, sq2[t] * (1.f / 65536.f));
    float a = g2[t] * rsqrtf(v + EPSV);
    bn[t][0] = a; bn[t][1] = fmaf(-a, m, be2[t]);
  }
  __syncthreads();
  size_t base = ((size_t)blockIdx.x * 256 + t) * 32;   // 32 halves/thread
  int c0 = (int)(base & 127);
  #pragma unroll
  for (int k = 0; k < 4; ++k) {
    ushort4 u0 = *(const ushort4*)(y2t + base + k * 8);
    ushort4 u1 = *(const ushort4*)(y2t + base + k * 8 + 4);
    int c = c0 + k * 8;
    float h0 = fmaxf(fmaf(bn[c+0][0], h2f(u0.x), bn[c+0][1]), 0.f);
    float h1 = fmaxf(fmaf(bn[c+1][0], h2f(u0.y), bn[c+1][1]), 0.f);
    float h2 = fmaxf(fmaf(bn[c+2][0], h2f(u0.z), bn[c+2][1]), 0.f);
    float h3 = fmaxf(fmaf(bn[c+3][0], h2f(u0.w), bn[c+3][1]), 0.f);
    float h4 = fmaxf(fmaf(bn[c+4][0], h2f(u1.x), bn[c+4][1]), 0.f);
    float h5 = fmaxf(fmaf(bn[c+5][0], h2f(u1.y), bn[c+5][1]), 0.f);
    float h6 = fmaxf(fmaf(bn[c+6][0], h2f(u1.z), bn[c+6][1]), 0.f);
    float h7 = fmaxf(fmaf(bn[c+7][0], h2f(u1.w), bn[c+7][1]), 0.f);
    uint4 pk;
    pk.x = (unsigned)f16r(h0) | ((unsigned)f16r(h1) << 16);
    pk.y = (unsigned)f16r(h2) | ((unsigned)f16r(h3) << 16);
    pk.z = (unsigned)f16r(h4) | ((unsigned)f16r(h5) << 16);
    pk.w = (unsigned)f16r(h6) | ((unsigned)f16r(h7) << 16);
    *(uint4*)(h2t + base + k * 8) = pk;
  }
}

// conv3 MFMA: block = (ot, b, n-half); 16 chunks of 64 n.
// A-frags direct from w3h (no LDS); dbuf h2s + register prefetch.
__global__ __launch_bounds__(256, 2) void k_conv3(const unsigned short* __restrict__ h2t,
    const unsigned short* __restrict__ w3h, const float* __restrict__ b3,
    float* __restrict__ mxb, float* __restrict__ mnb,
    float* __restrict__ sum3, float* __restrict__ sq3)
{
  __shared__ unsigned short h2s[2][16 * 64 * 8];// 2 x 16 KB
  __shared__ float sred[2][128][4];             // 4 KB
  int t = threadIdx.x;
  int bi = blockIdx.x;                 // 512: bi = ot*64 + b*2 + ns
  int ot_blk = bi >> 6;
  int b  = (bi >> 1) & 31;
  int ns = bi & 1;
  int o0 = ot_blk * 128;
  int n_base = ns * 1024;
  int w = t >> 6, lane = t & 63;
  int ow = w & 1, nw = w >> 1;
  int quad = lane >> 4, l15 = lane & 15;

  // A-frags: direct global loads (w3h 256KB, L2-hot across 512 blocks)
  half8 af[4][4];
  #pragma unroll
  for (int ti = 0; ti < 4; ++ti)
    #pragma unroll
    for (int s = 0; s < 4; ++s) {
      int cb = s * 4 + quad;
      int o = ow * 64 + ti * 16 + l15;
      af[ti][s] = *(const half8*)(w3h + (size_t)(o0 + o) * 128 + cb * 8);
    }

  float mx[4][4], mn[4][4], sm[4][4], sq[4][4];
  #pragma unroll
  for (int ti = 0; ti < 4; ++ti)
    #pragma unroll
    for (int r = 0; r < 4; ++r) {
      mx[ti][r] = -3.4e38f; mn[ti][r] = 3.4e38f; sm[ti][r] = 0.f; sq[ti][r] = 0.f;
    }

  int sn = t & 63, cq = t >> 6;        // staging map: 64 n x 4 cb-quads
  int cb0 = cq * 4;
  const unsigned short* sbase = h2t + ((size_t)b * NPT + n_base + sn) * C2 + cq * 32;
  // prologue: prefetch chunk 0 into regs
  uint4 v0 = *(const uint4*)(sbase);
  uint4 v1 = *(const uint4*)(sbase + 8);
  uint4 v2 = *(const uint4*)(sbase + 16);
  uint4 v3 = *(const uint4*)(sbase + 24);

  for (int nc = 0; nc < 16; ++nc) {
    unsigned short* buf = h2s[nc & 1];
    *(uint4*)&buf[((cb0 + 0) * 64 + SW(sn, cb0 + 0)) * 8] = v0;
    *(uint4*)&buf[((cb0 + 1) * 64 + SW(sn, cb0 + 1)) * 8] = v1;
    *(uint4*)&buf[((cb0 + 2) * 64 + SW(sn, cb0 + 2)) * 8] = v2;
    *(uint4*)&buf[((cb0 + 3) * 64 + SW(sn, cb0 + 3)) * 8] = v3;
    // issue prefetch for next chunk (clamped on last iter; completes during MFMA)
    {
      int nc1 = nc < 15 ? nc + 1 : 15;
      const unsigned short* src = sbase + (size_t)nc1 * 64 * C2;
      v0 = *(const uint4*)(src);
      v1 = *(const uint4*)(src + 8);
      v2 = *(const uint4*)(src + 16);
      v3 = *(const uint4*)(src + 24);
    }
    __syncthreads();

    const unsigned short* rbuf = h2s[nc & 1];
    floatx4 acc[4][2];
    #pragma unroll
    for (int ti = 0; ti < 4; ++ti)
      #pragma unroll
      for (int nt = 0; nt < 2; ++nt) acc[ti][nt] = (floatx4){0.f, 0.f, 0.f, 0.f};
    #pragma unroll
    for (int s = 0; s < 4; ++s) {
      int cb = s * 4 + quad;
      half8 bf[2];
      #pragma unroll
      for (int nt = 0; nt < 2; ++nt) {
        int n = nw * 32 + nt * 16 + l15;
        bf[nt] = *(const half8*)&rbuf[(cb * 64 + SW(n, cb)) * 8];
      }
      #pragma unroll
      for (int ti = 0; ti < 4; ++ti) {
        acc[ti][0] = __builtin_amdgcn_mfma_f32_16x16x32_f16(af[ti][s], bf[0], acc[ti][0], 0, 0, 0);
        acc[ti][1] = __builtin_amdgcn_mfma_f32_16x16x32_f16(af[ti][s], bf[1], acc[ti][1], 0, 0, 0);
      }
    }
    #pragma unroll
    for (int ti = 0; ti < 4; ++ti)
      #pragma unroll
      for (int nt = 0; nt < 2; ++nt)
        #pragma unroll
        for (int r = 0; r < 4; ++r) {
          float v = acc[ti][nt][r];
          mx[ti][r] = fmaxf(mx[ti][r], v);
          mn[ti][r] = fminf(mn[ti][r], v);
          sm[ti][r] += v;
          sq[ti][r] = fmaf(v, v, sq[ti][r]);
        }
  }

  #pragma unroll
  for (int ti = 0; ti < 4; ++ti)
    #pragma unroll
    for (int r = 0; r < 4; ++r) {
      #pragma unroll
      for (int m = 1; m < 16; m <<= 1) {
        mx[ti][r] = fmaxf(mx[ti][r], __shfl_xor(mx[ti][r], m, 16));
        mn[ti][r] = fminf(mn[ti][r], __shfl_xor(mn[ti][r], m, 16));
        sm[ti][r] += __shfl_xor(sm[ti][r], m, 16);
        sq[ti][r] += __shfl_xor(sq[ti][r], m, 16);
      }
    }
  if (l15 == 0) {
    #pragma unroll
    for (int ti = 0; ti < 4; ++ti)
      #pragma unroll
      for (int r = 0; r < 4; ++r) {
        int oloc = ow * 64 + ti * 16 + quad * 4 + r;
        sred[nw][oloc][0] = mx[ti][r];
        sred[nw][oloc][1] = mn[ti][r];
        sred[nw][oloc][2] = sm[ti][r];
        sred[nw][oloc][3] = sq[ti][r];
      }
  }
  __syncthreads();
  if (t < 128) {
    int o = o0 + t;
    float bo = b3[o];
    float fmx = fmaxf(sred[0][t][0], sred[1][t][0]) + bo;
    float fmn = fminf(sred[0][t][1], sred[1][t][1]) + bo;
    float smr = sred[0][t][2] + sred[1][t][2];
    float sqr = sred[0][t][3] + sred[1][t][3];
    mxb[ns * 32768 + b * 1024 + o] = fmx;
    mnb[ns * 32768 + b * 1024 + o] = fmn;
    atomicAdd(&sum3[o], fmaf(1024.f, bo, smr));
    atomicAdd(&sq3[o],  fmaf(1024.f * bo, bo, fmaf(2.f * bo, smr, sqr)));
  }
}

// FC1 + pooled fused: pool slice derived inline from mxb/mnb/sum3/sq3 (BN3).
__global__ __launch_bounds__(256) void k_fc1(const float* __restrict__ mxb,
    const float* __restrict__ mnb, const float* __restrict__ sum3,
    const float* __restrict__ sq3, const float* __restrict__ g3,
    const float* __restrict__ be3, const float* __restrict__ wf1,
    const float* __restrict__ bf1, float* __restrict__ f1r)
{
  __shared__ float ins[32 * 128];   // 16 KB
  __shared__ float bnA[128], bnS[128];
  int t = threadIdx.x;
  int f0 = blockIdx.x * 32;
  int k0 = blockIdx.y * 128;
  if (t < 128) {
    int c = k0 + t;
    float m = sum3[c] * (1.f / 65536.f);
    float v = fmaf(-m, m, sq3[c] * (1.f / 65536.f));
    float a = g3[c] * rsqrtf(v + EPSV);
    bnA[t] = a; bnS[t] = fmaf(-a, m, be3[c]);
  }
  __syncthreads();
  #pragma unroll
  for (int i = 0; i < 4; ++i) {
    int idx = i * 256 + t;
    int b = idx >> 5, k4 = idx & 31;
    float4 mxv = *(const float4*)(mxb + (size_t)b * 1024 + k0 + k4 * 4);
    float4 mx1 = *(const float4*)(mxb + 32768 + (size_t)b * 1024 + k0 + k4 * 4);
    float4 mnv = *(const float4*)(mnb + (size_t)b * 1024 + k0 + k4 * 4);
    float4 mn1 = *(const float4*)(mnb + 32768 + (size_t)b * 1024 + k0 + k4 * 4);
    float4 a = *(const float4*)&bnA[k4 * 4];
    float4 s = *(const float4*)&bnS[k4 * 4];
    float4 r;
    r.x = fmaf(a.x, (a.x >= 0.f ? fmaxf(mxv.x, mx1.x) : fminf(mnv.x, mn1.x)), s.x);
    r.y = fmaf(a.y, (a.y >= 0.f ? fmaxf(mxv.y, mx1.y) : fminf(mnv.y, mn1.y)), s.y);
    r.z = fmaf(a.z, (a.z >= 0.f ? fmaxf(mxv.z, mx1.z) : fminf(mnv.z, mn1.z)), s.z);
    r.w = fmaf(a.w, (a.w >= 0.f ? fmaxf(mxv.w, mx1.w) : fminf(mnv.w, mn1.w)), s.w);
    *(float4*)&ins[b * 128 + k4 * 4] = r;
  }
  __syncthreads();
  int f = t & 31, bq = t >> 5;
  int bl = bq * 4;
  const float4* wr = (const float4*)(wf1 + (size_t)(f0 + f) * 1024 + k0);
  float acc0 = 0.f, acc1 = 0.f, acc2 = 0.f, acc3 = 0.f;
  #pragma unroll 4
  for (int k4 = 0; k4 < 32; ++k4) {
    float4 wv = wr[k4];
    float4 i0 = *(const float4*)&ins[(bl + 0) * 128 + k4 * 4];
    float4 i1 = *(const float4*)&ins[(bl + 1) * 128 + k4 * 4];
    float4 i2 = *(const float4*)&ins[(bl + 2) * 128 + k4 * 4];
    float4 i3 = *(const float4*)&ins[(bl + 3) * 128 + k4 * 4];
    acc0 = fmaf(wv.x, i0.x, fmaf(wv.y, i0.y, fmaf(wv.z, i0.z, fmaf(wv.w, i0.w, acc0))));
    acc1 = fmaf(wv.x, i1.x, fmaf(wv.y, i1.y, fmaf(wv.z, i1.z, fmaf(wv.w, i1.w, acc1))));
    acc2 = fmaf(wv.x, i2.x, fmaf(wv.y, i2.y, fmaf(wv.z, i2.z, fmaf(wv.w, i2.w, acc2))));
    acc3 = fmaf(wv.x, i3.x, fmaf(wv.y, i3.y, fmaf(wv.z, i3.z, fmaf(wv.w, i3.w, acc3))));
  }
  float bs = (blockIdx.y == 0) ? bf1[f0 + f] : 0.f;
  atomicAdd(&f1r[(size_t)(bl + 0) * 512 + f0 + f], acc0 + bs);
  atomicAdd(&f1r[(size_t)(bl + 1) * 512 + f0 + f], acc1 + bs);
  atomicAdd(&f1r[(size_t)(bl + 2) * 512 + f0 + f], acc2 + bs);
  atomicAdd(&f1r[(size_t)(bl + 3) * 512 + f0 + f], acc3 + bs);
}

// FC2: BN1d(f1) stats inline per k-chunk; unroll capped at 4.
__global__ __launch_bounds__(256) void k_fc2(const float* __restrict__ f1r,
    const float* __restrict__ wf2, const float* __restrict__ bf2,
    const float* __restrict__ gf1, const float* __restrict__ bef1,
    float* __restrict__ f2r)
{
  __shared__ float ins[32 * 64];    // 8 KB
  __shared__ float bnA[64], bnS[64];
  int t = threadIdx.x;
  int f0 = blockIdx.x * 32;
  int k0 = blockIdx.y * 64;
  #pragma unroll
  for (int i = 0; i < 2; ++i) {
    int idx = i * 256 + t;
    int b = idx >> 4, k4 = idx & 15;
    *(float4*)&ins[b * 64 + k4 * 4] = *(const float4*)(f1r + (size_t)b * 512 + k0 + k4 * 4);
  }
  __syncthreads();
  if (t < 64) {
    float s = 0.f, q = 0.f;
    #pragma unroll
    for (int b = 0; b < 32; ++b) {
      float xx = ins[b * 64 + t];
      s += xx; q = fmaf(xx, xx, q);
    }
    float m = s * (1.f / 32.f);
    float v = fmaf(-m, m, q * (1.f / 32.f));
    float a = gf1[k0 + t] * rsqrtf(v + EPSV);
    bnA[t] = a; bnS[t] = fmaf(-a, m, bef1[k0 + t]);
  }
  __syncthreads();
  #pragma unroll
  for (int i = 0; i < 2; ++i) {
    int idx = i * 256 + t;
    int b = idx >> 4, k4 = idx & 15;
    float4 v = *(const float4*)&ins[b * 64 + k4 * 4];
    v.x = fmaxf(fmaf(bnA[k4*4+0], v.x, bnS[k4*4+0]), 0.f);
    v.y = fmaxf(fmaf(bnA[k4*4+1], v.y, bnS[k4*4+1]), 0.f);
    v.z = fmaxf(fmaf(bnA[k4*4+2], v.z, bnS[k4*4+2]), 0.f);
    v.w = fmaxf(fmaf(bnA[k4*4+3], v.w, bnS[k4*4+3]), 0.f);
    *(float4*)&ins[b * 64 + k4 * 4] = v;
  }
  __syncthreads();
  int f = t & 31, bq = t >> 5;
  int bl = bq * 4;
  const float4* wr = (const float4*)(wf2 + (size_t)(f0 + f) * 512 + k0);
  float acc0 = 0.f, acc1 = 0.f, acc2 = 0.f, acc3 = 0.f;
  #pragma unroll 4
  for (int k4 = 0; k4 < 16; ++k4) {
    float4 wv = wr[k4];
    float4 i0 = *(const float4*)&ins[(bl + 0) * 64 + k4 * 4];
    float4 i1 = *(const float4*)&ins[(bl + 1) * 64 + k4 * 4];
    float4 i2 = *(const float4*)&ins[(bl + 2) * 64 + k4 * 4];
    float4 i3 = *(const float4*)&ins[(bl + 3) * 64 + k4 * 4];
    acc0 = fmaf(wv.x, i0.x, fmaf(wv.y, i0.y, fmaf(wv.z, i0.z, fmaf(wv.w, i0.w, acc0))));
    acc1 = fmaf(wv.x, i1.x, fmaf(wv.y, i1.y, fmaf(wv.z, i1.z, fmaf(wv.w, i1.w, acc1))));
    acc2 = fmaf(wv.x, i2.x, fmaf(wv.y, i2.y, fmaf(wv.z, i2.z, fmaf(wv.w, i2.w, acc2))));
    acc3 = fmaf(wv.x, i3.x, fmaf(wv.y, i3.y, fmaf(wv.z, i3.z, fmaf(wv.w, i3.w, acc3))));
  }
  float bs = (blockIdx.y == 0) ? bf2[f0 + f] : 0.f;
  atomicAdd(&f2r[(size_t)(bl + 0) * 256 + f0 + f], acc0 + bs);
  atomicAdd(&f2r[(size_t)(bl + 1) * 256 + f0 + f], acc1 + bs);
  atomicAdd(&f2r[(size_t)(bl + 2) * 256 + f0 + f], acc2 + bs);
  atomicAdd(&f2r[(size_t)(bl + 3) * 256 + f0 + f], acc3 + bs);
}

// Head: BN-F2 stats inline; p = relu(BN(f2r)) @ wp.T + bp; Horn SO(3) -> [B,4,4].
__global__ __launch_bounds__(384) void k_head(const float* __restrict__ f2r,
    const float* __restrict__ gf2, const float* __restrict__ bef2,
    const float* __restrict__ wp, const float* __restrict__ bp,
    float* __restrict__ out)
{
  __shared__ float pS[32 * 12];
  __shared__ float bnf[256][2];
  int t = threadIdx.x;
  if (t < 256) {
    float s = 0.f, q = 0.f;
    #pragma unroll
    for (int b = 0; b < 32; ++b) {
      float xx = f2r[b * 256 + t];
      s += xx; q = fmaf(xx, xx, q);
    }
    float m = s * (1.f / 32.f);
    float v = fmaf(-m, m, q * (1.f / 32.f));
    float a = gf2[t] * rsqrtf(v + EPSV);
    bnf[t][0] = a; bnf[t][1] = fmaf(-a, m, bef2[t]);
  }
  __syncthreads();
  {
    int b = t / 12, j = t % 12;
    const float* w = wp + j * 256;
    const float* fr = f2r + b * 256;
    float acc = bp[j];
    #pragma unroll 8
    for (int c = 0; c < 256; ++c) {
      float h = fmaxf(fmaf(bnf[c][0], fr[c], bnf[c][1]), 0.f);
      acc = fmaf(w[c], h, acc);
    }
    pS[t] = acc;
  }
  __syncthreads();
  if (t < 32) {
    const float* p = &pS[t * 12];
    float m00=p[0],m01=p[1],m02=p[2],m10=p[3],m11=p[4],m12=p[5],m20=p[6],m21=p[7],m22=p[8];
    float P[4][4];
    P[0][0]=m00+m11+m22; P[0][1]=m21-m12;     P[0][2]=m02-m20;     P[0][3]=m10-m01;
    P[1][1]=m00-m11-m22; P[1][2]=m01+m10;     P[1][3]=m02+m20;
    P[2][2]=m11-m00-m22; P[2][3]=m12+m21;
    P[3][3]=m22-m00-m11;
    P[1][0]=P[0][1]; P[2][0]=P[0][2]; P[3][0]=P[0][3];
    P[2][1]=P[1][2]; P[3][1]=P[1][3]; P[3][2]=P[2][3];
    float fn = sqrtf(m00*m00+m01*m01+m02*m02+m10*m10+m11*m11+m12*m12+m20*m20+m21*m21+m22*m22);
    float inv = 1.f / (2.f * fn + 1e-30f);
    #pragma unroll
    for (int i = 0; i < 4; ++i)
      #pragma unroll
      for (int j = 0; j < 4; ++j) P[i][j] *= inv;
    P[0][0] += 1.f; P[1][1] += 1.f; P[2][2] += 1.f; P[3][3] += 1.f;
    for (int it = 0; it < 16; ++it) {
      float Q[4][4];
      #pragma unroll
      for (int i = 0; i < 4; ++i)
        #pragma unroll
        for (int j = 0; j < 4; ++j)
          Q[i][j] = P[i][0]*P[0][j] + P[i][1]*P[1][j] + P[i][2]*P[2][j] + P[i][3]*P[3][j];
      float mxa = 0.f;
      #pragma unroll
      for (int i = 0; i < 4; ++i)
        #pragma unroll
        for (int j = 0; j < 4; ++j) mxa = fmaxf(mxa, fabsf(Q[i][j]));
      float r = 1.f / mxa;
      #pragma unroll
      for (int i = 0; i < 4; ++i)
        #pragma unroll
        for (int j = 0; j < 4; ++j) P[i][j] = Q[i][j] * r;
    }
    float bestn = -1.f; int bj = 0;
    #pragma unroll
    for (int j = 0; j < 4; ++j) {
      float nn = P[0][j]*P[0][j] + P[1][j]*P[1][j] + P[2][j]*P[2][j] + P[3][j]*P[3][j];
      if (nn > bestn) { bestn = nn; bj = j; }
    }
    float qw = P[0][bj], qx = P[1][bj], qy = P[2][bj], qz = P[3][bj];
    float qn = rsqrtf(qw*qw + qx*qx + qy*qy + qz*qz);
    qw *= qn; qx *= qn; qy *= qn; qz *= qn;
    float* ob = out + t * 16;
    ob[0]  = 1.f - 2.f*(qy*qy + qz*qz);
    ob[1]  = 2.f*(qx*qy - qw*qz);
    ob[2]  = 2.f*(qx*qz + qw*qy);
    ob[3]  = p[9];
    ob[4]  = 2.f*(qx*qy + qw*qz);
    ob[5]  = 1.f - 2.f*(qx*qx + qz*qz);
    ob[6]  = 2.f*(qy*qz - qw*qx);
    ob[7]  = p[10];
    ob[8]  = 2.f*(qx*qz - qw*qy);
    ob[9]  = 2.f*(qy*qz + qw*qx);
    ob[10] = 1.f - 2.f*(qx*qx + qy*qy);
    ob[11] = p[11];
    ob[12] = 0.f; ob[13] = 0.f; ob[14] = 0.f; ob[15] = 1.f;
  }
}

extern "C" void kernel_launch(void* const* d_in, const int* in_sizes, int n_in,
                              void* d_out, int out_size, void* d_ws, size_t ws_size,
                              hipStream_t stream)
{
  (void)in_sizes; (void)n_in; (void)out_size;
  if (ws_size < (size_t)WS_FLOATS * sizeof(float)) return;
  const float* x   = (const float*)d_in[0];
  const float* w1  = (const float*)d_in[1];
  const float* b1  = (const float*)d_in[2];
  const float* g1  = (const float*)d_in[3];
  const float* be1 = (const float*)d_in[4];
  const float* w2  = (const float*)d_in[5];
  const float* b2  = (const float*)d_in[6];
  const float* g2  = (const float*)d_in[7];
  const float* be2 = (const float*)d_in[8];
  const float* w3  = (const float*)d_in[9];
  const float* b3  = (const float*)d_in[10];
  const float* g3  = (const float*)d_in[11];
  const float* be3 = (const float*)d_in[12];
  const float* wf1 = (const float*)d_in[13];
  const float* bf1 = (const float*)d_in[14];
  const float* gf1 = (const float*)d_in[15];
  const float* bef1= (const float*)d_in[16];
  const float* wf2 = (const float*)d_in[17];
  const float* bf2 = (const float*)d_in[18];
  const float* gf2 = (const float*)d_in[19];
  const float* bef2= (const float*)d_in[20];
  const float* wp  = (const float*)d_in[21];
  const float* bp  = (const float*)d_in[22];
  float* ws  = (float*)d_ws;
  float* out = (float*)d_out;
  unsigned short* y2t = (unsigned short*)(ws + OFF_Y2T);
  unsigned short* h2t = (unsigned short*)(ws + OFF_H2T);
  unsigned short* w3h = (unsigned short*)(ws + OFF_W3H);

  hipMemsetAsync((void*)(ws + OFF_Z), 0, ZN * sizeof(float), stream);
  k_prep<<<192, 256, 0, stream>>>(w3, w3h, x, ws + OFF_XS);
  k_conv12<<<1024, 256, 0, stream>>>(x, w1, b1, g1, be1, ws + OFF_XS,
                                     w2, b2, y2t, ws + OFF_SUM2, ws + OFF_SQ2);
  k_bnrelu2<<<1024, 256, 0, stream>>>(y2t, ws + OFF_SUM2, ws + OFF_SQ2, g2, be2, h2t);
  k_conv3<<<512, 256, 0, stream>>>(h2t, w3h, b3, ws + OFF_MX, ws + OFF_MN,
                                   ws + OFF_SUM3, ws + OFF_SQ3);
  k_fc1<<<dim3(16, 8), 256, 0, stream>>>(ws + OFF_MX, ws + OFF_MN, ws + OFF_SUM3,
                                         ws + OFF_SQ3, g3, be3, wf1, bf1, ws + OFF_F1R);
  k_fc2<<<dim3(8, 8), 256, 0, stream>>>(ws + OFF_F1R, wf2, bf2, gf1, bef1, ws + OFF_F2R);
  k_head<<<1, 384, 0, stream>>>(ws + OFF_F2R, gf2, bef2, wp, bp, out);
}

// Round 11
// 202.908 us; speedup vs baseline: 1.0412x; 1.0412x over previous
//
#include <hip/hip_runtime.h>

// PointNetRot9d. Round 11: REVERT to r9 exactly (best measured: 205.4 us).
//  - r10's A-operand direct-global-load (no LDS stage) regressed +6us:
//    fragment loads are 256B-strided across lanes (64 cache lines per half8
//    frag, 16 frags/wave at block start) vs coalesced staging + LDS broadcast.
//    Post-mortem rule: prediction missed and it hurt -> revert.
//  - r9 config: conv12 (fused conv1+BN1-closed-form -> conv2 MFMA, w2h fp16
//    LDS-staged), y2t/h2t transposed fp16, bnrelu2 elementwise, conv3 with
//    LDS-staged w3s A-operand + double-buffered h2s + register prefetch,
//    pooled fused into fc1, fc unroll capped at 4. 8 dispatches.

#define NPT 2048
#define C1 64
#define C2 128
#define EPSV 1e-5f

typedef __attribute__((ext_vector_type(8))) _Float16 half8;
typedef __attribute__((ext_vector_type(4))) float floatx4;

// ---- workspace layout (float-slot offsets) ----
#define OFF_Y2T   0               // 32*2048*128 halves = 4194304 slots
#define OFF_H2T   4194304         // 32*2048*128 halves = 4194304 slots
#define OFF_Z     8388608         // zeroed region start
#define OFF_XS    (OFF_Z)         // 16: Sx[3], Sxx diag[3], Sxx off[3]
#define OFF_SUM2  (OFF_Z+16)
#define OFF_SQ2   (OFF_Z+144)
#define OFF_SUM3  (OFF_Z+272)
#define OFF_SQ3   (OFF_Z+1296)
#define OFF_F1R   (OFF_Z+2320)    // 32*512
#define OFF_F2R   (OFF_Z+18704)   // 32*256
#define ZN        26896
#define OFF_MX    (OFF_Z+26896)   // 2 ns-slots * 32*1024
#define OFF_MN    (OFF_MX+65536)
#define OFF_W3H   (OFF_MN+65536)  // 131072 halves = 65536 slots
#define OFF_W2H   (OFF_W3H+65536) // 8192 halves = 4096 slots
#define WS_FLOATS (OFF_W2H+4096)  // 8,550,160 floats = 34.2 MB

static __device__ inline unsigned short f16r(float f) {
  _Float16 h = (_Float16)f;
  return __builtin_bit_cast(unsigned short, h);
}
static __device__ inline float h2f(unsigned short u) {
  return (float)__builtin_bit_cast(_Float16, u);
}
// LDS staging swizzle (bijection on n per cb): conflict-free b128 write+read.
static __device__ inline int SW(int n, int cb) { return n ^ (((n >> 3) ^ cb) & 7); }

// k_prep: blocks [0,136) cvt w3/w2 -> fp16; blocks [136,200) x moments.
__global__ __launch_bounds__(256) void k_prep(const float* __restrict__ w3,
    const float* __restrict__ w2, unsigned short* __restrict__ w3h,
    unsigned short* __restrict__ w2h, const float* __restrict__ x,
    float* __restrict__ xs)
{
  int bi = blockIdx.x;
  int t = threadIdx.x;
  if (bi < 136) {
    int idx4 = bi * 256 + t;                   // 34816 f4
    const float4* src; ushort4* dst; int k;
    if (idx4 < 32768) { src = (const float4*)w3; dst = (ushort4*)w3h; k = idx4; }
    else               { src = (const float4*)w2; dst = (ushort4*)w2h; k = idx4 - 32768; }
    float4 v = src[k];
    ushort4 o;
    o.x = f16r(v.x); o.y = f16r(v.y); o.z = f16r(v.z); o.w = f16r(v.w);
    dst[k] = o;
    return;
  }
  int idx4 = (bi - 136) * 256 + t;             // 16384 f4 = [32 b][512 n4]
  int n4 = idx4 & 511, b = idx4 >> 9;
  const float4* xr = (const float4*)(x + (size_t)b * 3 * NPT);
  float4 x0 = xr[n4], x1 = xr[512 + n4], x2 = xr[1024 + n4];
  float v[9];
  v[0] = x0.x + x0.y + x0.z + x0.w;
  v[1] = x1.x + x1.y + x1.z + x1.w;
  v[2] = x2.x + x2.y + x2.z + x2.w;
  v[3] = x0.x*x0.x + x0.y*x0.y + x0.z*x0.z + x0.w*x0.w;
  v[4] = x1.x*x1.x + x1.y*x1.y + x1.z*x1.z + x1.w*x1.w;
  v[5] = x2.x*x2.x + x2.y*x2.y + x2.z*x2.z + x2.w*x2.w;
  v[6] = x0.x*x1.x + x0.y*x1.y + x0.z*x1.z + x0.w*x1.w;
  v[7] = x0.x*x2.x + x0.y*x2.y + x0.z*x2.z + x0.w*x2.w;
  v[8] = x1.x*x2.x + x1.y*x2.y + x1.z*x2.z + x1.w*x2.w;
  #pragma unroll
  for (int k = 0; k < 9; ++k)
    for (int off = 32; off; off >>= 1) v[k] += __shfl_down(v[k], off);
  __shared__ float red[4][9];
  int lane = t & 63, wv = t >> 6;
  if (!lane)
    #pragma unroll
    for (int k = 0; k < 9; ++k) red[wv][k] = v[k];
  __syncthreads();
  if (t < 9)
    atomicAdd(&xs[t], red[0][t] + red[1][t] + red[2][t] + red[3][t]);
}

// k_conv12: fused conv1(+BN1 closed form +relu, in-register) -> conv2 MFMA.
// Block = (b, 64-n slice) x all 128 o. y2t [b][n][128c] fp16 raw + BN2 stats.
__global__ __launch_bounds__(256, 4) void k_conv12(const float* __restrict__ x,
    const float* __restrict__ w1, const float* __restrict__ b1,
    const float* __restrict__ g1, const float* __restrict__ be1,
    const float* __restrict__ xs,
    const unsigned short* __restrict__ w2h, const float* __restrict__ b2,
    unsigned short* __restrict__ y2t, float* __restrict__ sum2, float* __restrict__ sq2)
{
  __shared__ unsigned short w2s[8 * 128 * 8];   // 16 KB
  __shared__ unsigned short h1s[8 * 64 * 8];    // 8 KB
  __shared__ float wc[64][4];
  __shared__ float sred[2][128][2];
  int t = threadIdx.x;
  int bi = blockIdx.x;                 // 1024 = 32 b x 32 ns
  int b = bi >> 5, ns = bi & 31;
  int n0 = ns * 64;
  int w = t >> 6, lane = t & 63;
  int ow = w & 1, nw = w >> 1;
  int quad = lane >> 4, l15 = lane & 15;

  // A: BN1 closed form -> folded conv1 coeffs
  if (t < 64) {
    float w0 = w1[t*3], w1_ = w1[t*3+1], w2_ = w1[t*3+2], bb = b1[t];
    const float invN = 1.f / 65536.f;
    float wsx = (w0*xs[0] + w1_*xs[1] + w2_*xs[2]) * invN;
    float mean = wsx + bb;
    float Ey2 = (w0*w0*xs[3] + w1_*w1_*xs[4] + w2_*w2_*xs[5]
               + 2.f*(w0*w1_*xs[6] + w0*w2_*xs[7] + w1_*w2_*xs[8])) * invN
               + 2.f*bb*wsx + bb*bb;
    float var = Ey2 - mean*mean;
    float a = g1[t] * rsqrtf(var + EPSV);
    wc[t][0] = a*w0; wc[t][1] = a*w1_; wc[t][2] = a*w2_;
    wc[t][3] = be1[t] + a*(bb - mean);
  }
  // B: stage w2 [cb][o'][8], o' = (o+cb)&127
  for (int i = 0; i < 4; ++i) {
    int idx = i * 256 + t;             // 1024 = 128 o x 8 cb
    int o = idx >> 3, cb = idx & 7;
    uint4 v = *(const uint4*)(w2h + o * 64 + cb * 8);
    int op = (o + cb) & 127;
    *(uint4*)&w2s[(cb * 128 + op) * 8] = v;
  }
  __syncthreads();                     // wc ready for C

  // C: compute h1 = relu(wc . x) for 8c x 2n per thread; pack to swizzled LDS
  {
    int cg = t >> 5, ng = t & 31;      // 8 c-groups x 32 n-pairs
    int c0 = cg * 8, nn = ng * 2;
    const float* xb = x + (size_t)b * 3 * NPT + n0 + nn;
    float2 xv0 = *(const float2*)(xb);
    float2 xv1 = *(const float2*)(xb + NPT);
    float2 xv2 = *(const float2*)(xb + 2 * NPT);
    uint4 p0, p1;
    unsigned* a0 = (unsigned*)&p0;
    unsigned* a1 = (unsigned*)&p1;
    #pragma unroll
    for (int j = 0; j < 4; ++j) {
      int c = c0 + j * 2;
      float hA0 = fmaxf(fmaf(wc[c][0], xv0.x, fmaf(wc[c][1], xv1.x, fmaf(wc[c][2], xv2.x, wc[c][3]))), 0.f);
      float hA1 = fmaxf(fmaf(wc[c][0], xv0.y, fmaf(wc[c][1], xv1.y, fmaf(wc[c][2], xv2.y, wc[c][3]))), 0.f);
      float hB0 = fmaxf(fmaf(wc[c+1][0], xv0.x, fmaf(wc[c+1][1], xv1.x, fmaf(wc[c+1][2], xv2.x, wc[c+1][3]))), 0.f);
      float hB1 = fmaxf(fmaf(wc[c+1][0], xv0.y, fmaf(wc[c+1][1], xv1.y, fmaf(wc[c+1][2], xv2.y, wc[c+1][3]))), 0.f);
      a0[j] = (unsigned)f16r(hA0) | ((unsigned)f16r(hB0) << 16);
      a1[j] = (unsigned)f16r(hA1) | ((unsigned)f16r(hB1) << 16);
    }
    *(uint4*)&h1s[(cg * 64 + SW(nn, cg)) * 8] = p0;
    *(uint4*)&h1s[(cg * 64 + SW(nn + 1, cg)) * 8] = p1;
  }
  __syncthreads();

  half8 af[4][2];
  #pragma unroll
  for (int ti = 0; ti < 4; ++ti)
    #pragma unroll
    for (int s = 0; s < 2; ++s) {
      int cb = s * 4 + quad;
      int o = ow * 64 + ti * 16 + l15;
      int op = (o + cb) & 127;
      af[ti][s] = *(const half8*)&w2s[(cb * 128 + op) * 8];
    }
  float breg[4][4];
  #pragma unroll
  for (int ti = 0; ti < 4; ++ti)
    #pragma unroll
    for (int r = 0; r < 4; ++r)
      breg[ti][r] = b2[ow * 64 + ti * 16 + quad * 4 + r];

  floatx4 acc[4][2];
  #pragma unroll
  for (int ti = 0; ti < 4; ++ti)
    #pragma unroll
    for (int nt = 0; nt < 2; ++nt) acc[ti][nt] = (floatx4){0.f, 0.f, 0.f, 0.f};
  #pragma unroll
  for (int s = 0; s < 2; ++s) {
    int cb = s * 4 + quad;
    half8 bf[2];
    #pragma unroll
    for (int nt = 0; nt < 2; ++nt) {
      int n = nw * 32 + nt * 16 + l15;
      bf[nt] = *(const half8*)&h1s[(cb * 64 + SW(n, cb)) * 8];
    }
    #pragma unroll
    for (int ti = 0; ti < 4; ++ti) {
      acc[ti][0] = __builtin_amdgcn_mfma_f32_16x16x32_f16(af[ti][s], bf[0], acc[ti][0], 0, 0, 0);
      acc[ti][1] = __builtin_amdgcn_mfma_f32_16x16x32_f16(af[ti][s], bf[1], acc[ti][1], 0, 0, 0);
    }
  }

  // epilogue: y2t[b][n][c] = fp16(acc + b2) via 8B stores; exact fp32 stats
  float sm[4][4], sq[4][4];
  #pragma unroll
  for (int ti = 0; ti < 4; ++ti)
    #pragma unroll
    for (int r = 0; r < 4; ++r) { sm[ti][r] = 0.f; sq[ti][r] = 0.f; }
  #pragma unroll
  for (int ti = 0; ti < 4; ++ti) {
    int o = ow * 64 + ti * 16 + quad * 4;
    #pragma unroll
    for (int nt = 0; nt < 2; ++nt) {
      int n = n0 + nw * 32 + nt * 16 + l15;
      float v0 = acc[ti][nt][0] + breg[ti][0];
      float v1 = acc[ti][nt][1] + breg[ti][1];
      float v2 = acc[ti][nt][2] + breg[ti][2];
      float v3 = acc[ti][nt][3] + breg[ti][3];
      ushort4 st;
      st.x = f16r(v0); st.y = f16r(v1); st.z = f16r(v2); st.w = f16r(v3);
      *(ushort4*)(y2t + ((size_t)b * NPT + n) * C2 + o) = st;
      sm[ti][0] += v0; sq[ti][0] = fmaf(v0, v0, sq[ti][0]);
      sm[ti][1] += v1; sq[ti][1] = fmaf(v1, v1, sq[ti][1]);
      sm[ti][2] += v2; sq[ti][2] = fmaf(v2, v2, sq[ti][2]);
      sm[ti][3] += v3; sq[ti][3] = fmaf(v3, v3, sq[ti][3]);
    }
  }
  #pragma unroll
  for (int ti = 0; ti < 4; ++ti)
    #pragma unroll
    for (int r = 0; r < 4; ++r) {
      #pragma unroll
      for (int m = 1; m < 16; m <<= 1) {
        sm[ti][r] += __shfl_xor(sm[ti][r], m, 16);
        sq[ti][r] += __shfl_xor(sq[ti][r], m, 16);
      }
    }
  if (l15 == 0) {
    #pragma unroll
    for (int ti = 0; ti < 4; ++ti)
      #pragma unroll
      for (int r = 0; r < 4; ++r) {
        int oloc = ow * 64 + ti * 16 + quad * 4 + r;
        sred[nw][oloc][0] = sm[ti][r];
        sred[nw][oloc][1] = sq[ti][r];
      }
  }
  __syncthreads();
  if (t < 128) {
    atomicAdd(&sum2[t], sred[0][t][0] + sred[1][t][0]);
    atomicAdd(&sq2[t],  sred[0][t][1] + sred[1][t][1]);
  }
}

// BN2+relu elementwise (linear, same layout): y2t -> h2t, fp32 BN math.
__global__ __launch_bounds__(256) void k_bnrelu2(const unsigned short* __restrict__ y2t,
    const float* __restrict__ sum2, const float* __restrict__ sq2,
    const float* __restrict__ g2, const float* __restrict__ be2,
    unsigned short* __restrict__ h2t)
{
  __shared__ float bn[128][2];
  int t = threadIdx.x;
  if (t < 128) {
    float m = sum2[t] * (1.f / 65536.f);
    float v = fmaf(-m, m, sq2[t] * (1.f / 65536.f));
    float a = g2[t] * rsqrtf(v + EPSV);
    bn[t][0] = a; bn[t][1] = fmaf(-a, m, be2[t]);
  }
  __syncthreads();
  size_t base = ((size_t)blockIdx.x * 256 + t) * 32;   // 32 halves/thread
  int c0 = (int)(base & 127);
  #pragma unroll
  for (int k = 0; k < 4; ++k) {
    ushort4 u0 = *(const ushort4*)(y2t + base + k * 8);
    ushort4 u1 = *(const ushort4*)(y2t + base + k * 8 + 4);
    int c = c0 + k * 8;
    float h0 = fmaxf(fmaf(bn[c+0][0], h2f(u0.x), bn[c+0][1]), 0.f);
    float h1 = fmaxf(fmaf(bn[c+1][0], h2f(u0.y), bn[c+1][1]), 0.f);
    float h2 = fmaxf(fmaf(bn[c+2][0], h2f(u0.z), bn[c+2][1]), 0.f);
    float h3 = fmaxf(fmaf(bn[c+3][0], h2f(u0.w), bn[c+3][1]), 0.f);
    float h4 = fmaxf(fmaf(bn[c+4][0], h2f(u1.x), bn[c+4][1]), 0.f);
    float h5 = fmaxf(fmaf(bn[c+5][0], h2f(u1.y), bn[c+5][1]), 0.f);
    float h6 = fmaxf(fmaf(bn[c+6][0], h2f(u1.z), bn[c+6][1]), 0.f);
    float h7 = fmaxf(fmaf(bn[c+7][0], h2f(u1.w), bn[c+7][1]), 0.f);
    uint4 pk;
    pk.x = (unsigned)f16r(h0) | ((unsigned)f16r(h1) << 16);
    pk.y = (unsigned)f16r(h2) | ((unsigned)f16r(h3) << 16);
    pk.z = (unsigned)f16r(h4) | ((unsigned)f16r(h5) << 16);
    pk.w = (unsigned)f16r(h6) | ((unsigned)f16r(h7) << 16);
    *(uint4*)(h2t + base + k * 8) = pk;
  }
}

// conv3 MFMA: block = (ot, b, n-half); 16 chunks of 64 n.
// DOUBLE-BUFFERED LDS + register prefetch: one barrier per chunk, next
// chunk's global loads issued during MFMA phase. Stats on RAW acc.
__global__ __launch_bounds__(256, 2) void k_conv3(const unsigned short* __restrict__ h2t,
    const unsigned short* __restrict__ w3h, const float* __restrict__ b3,
    float* __restrict__ mxb, float* __restrict__ mnb,
    float* __restrict__ sum3, float* __restrict__ sq3)
{
  __shared__ unsigned short w3s[16 * 128 * 8];  // 32 KB
  __shared__ unsigned short h2s[2][16 * 64 * 8];// 2 x 16 KB
  __shared__ float sred[2][128][4];             // 4 KB
  int t = threadIdx.x;
  int bi = blockIdx.x;                 // 512: bi = ot*64 + b*2 + ns
  int ot_blk = bi >> 6;
  int b  = (bi >> 1) & 31;
  int ns = bi & 1;
  int o0 = ot_blk * 128;
  int n_base = ns * 1024;
  int w = t >> 6, lane = t & 63;
  int ow = w & 1, nw = w >> 1;
  int quad = lane >> 4, l15 = lane & 15;

  for (int i = 0; i < 8; ++i) {
    int idx = i * 256 + t;             // 2048 = 128 o x 16 cb
    int o = idx >> 4, cb = idx & 15;
    uint4 v = *(const uint4*)(w3h + (size_t)(o0 + o) * 128 + cb * 8);
    int op = (o + cb) & 127;
    *(uint4*)&w3s[(cb * 128 + op) * 8] = v;
  }
  __syncthreads();

  half8 af[4][4];
  #pragma unroll
  for (int ti = 0; ti < 4; ++ti)
    #pragma unroll
    for (int s = 0; s < 4; ++s) {
      int cb = s * 4 + quad;
      int o = ow * 64 + ti * 16 + l15;
      int op = (o + cb) & 127;
      af[ti][s] = *(const half8*)&w3s[(cb * 128 + op) * 8];
    }

  float mx[4][4], mn[4][4], sm[4][4], sq[4][4];
  #pragma unroll
  for (int ti = 0; ti < 4; ++ti)
    #pragma unroll
    for (int r = 0; r < 4; ++r) {
      mx[ti][r] = -3.4e38f; mn[ti][r] = 3.4e38f; sm[ti][r] = 0.f; sq[ti][r] = 0.f;
    }

  int sn = t & 63, cq = t >> 6;        // staging map: 64 n x 4 cb-quads
  int cb0 = cq * 4;
  const unsigned short* sbase = h2t + ((size_t)b * NPT + n_base + sn) * C2 + cq * 32;
  // prologue: prefetch chunk 0 into regs
  uint4 v0 = *(const uint4*)(sbase);
  uint4 v1 = *(const uint4*)(sbase + 8);
  uint4 v2 = *(const uint4*)(sbase + 16);
  uint4 v3 = *(const uint4*)(sbase + 24);

  for (int nc = 0; nc < 16; ++nc) {
    unsigned short* buf = h2s[nc & 1];
    *(uint4*)&buf[((cb0 + 0) * 64 + SW(sn, cb0 + 0)) * 8] = v0;
    *(uint4*)&buf[((cb0 + 1) * 64 + SW(sn, cb0 + 1)) * 8] = v1;
    *(uint4*)&buf[((cb0 + 2) * 64 + SW(sn, cb0 + 2)) * 8] = v2;
    *(uint4*)&buf[((cb0 + 3) * 64 + SW(sn, cb0 + 3)) * 8] = v3;
    // issue prefetch for next chunk (clamped on last iter; completes during MFMA)
    {
      int nc1 = nc < 15 ? nc + 1 : 15;
      const unsigned short* src = sbase + (size_t)nc1 * 64 * C2;
      v0 = *(const uint4*)(src);
      v1 = *(const uint4*)(src + 8);
      v2 = *(const uint4*)(src + 16);
      v3 = *(const uint4*)(src + 24);
    }
    __syncthreads();

    const unsigned short* rbuf = h2s[nc & 1];
    floatx4 acc[4][2];
    #pragma unroll
    for (int ti = 0; ti < 4; ++ti)
      #pragma unroll
      for (int nt = 0; nt < 2; ++nt) acc[ti][nt] = (floatx4){0.f, 0.f, 0.f, 0.f};
    #pragma unroll
    for (int s = 0; s < 4; ++s) {
      int cb = s * 4 + quad;
      half8 bf[2];
      #pragma unroll
      for (int nt = 0; nt < 2; ++nt) {
        int n = nw * 32 + nt * 16 + l15;
        bf[nt] = *(const half8*)&rbuf[(cb * 64 + SW(n, cb)) * 8];
      }
      #pragma unroll
      for (int ti = 0; ti < 4; ++ti) {
        acc[ti][0] = __builtin_amdgcn_mfma_f32_16x16x32_f16(af[ti][s], bf[0], acc[ti][0], 0, 0, 0);
        acc[ti][1] = __builtin_amdgcn_mfma_f32_16x16x32_f16(af[ti][s], bf[1], acc[ti][1], 0, 0, 0);
      }
    }
    #pragma unroll
    for (int ti = 0; ti < 4; ++ti)
      #pragma unroll
      for (int nt = 0; nt < 2; ++nt)
        #pragma unroll
        for (int r = 0; r < 4; ++r) {
          float v = acc[ti][nt][r];
          mx[ti][r] = fmaxf(mx[ti][r], v);
          mn[ti][r] = fminf(mn[ti][r], v);
          sm[ti][r] += v;
          sq[ti][r] = fmaf(v, v, sq[ti][r]);
        }
  }

  #pragma unroll
  for (int ti = 0; ti < 4; ++ti)
    #pragma unroll
    for (int r = 0; r < 4; ++r) {
      #pragma unroll
      for (int m = 1; m < 16; m <<= 1) {
        mx[ti][r] = fmaxf(mx[ti][r], __shfl_xor(mx[ti][r], m, 16));
        mn[ti][r] = fminf(mn[ti][r], __shfl_xor(mn[ti][r], m, 16));
        sm[ti][r] += __shfl_xor(sm[ti][r], m, 16);
        sq[ti][r] += __shfl_xor(sq[ti][r], m, 16);
      }
    }
  if (l15 == 0) {
    #pragma unroll
    for (int ti = 0; ti < 4; ++ti)
      #pragma unroll
      for (int r = 0; r < 4; ++r) {
        int oloc = ow * 64 + ti * 16 + quad * 4 + r;
        sred[nw][oloc][0] = mx[ti][r];
        sred[nw][oloc][1] = mn[ti][r];
        sred[nw][oloc][2] = sm[ti][r];
        sred[nw][oloc][3] = sq[ti][r];
      }
  }
  __syncthreads();
  if (t < 128) {
    int o = o0 + t;
    float bo = b3[o];
    float fmx = fmaxf(sred[0][t][0], sred[1][t][0]) + bo;
    float fmn = fminf(sred[0][t][1], sred[1][t][1]) + bo;
    float smr = sred[0][t][2] + sred[1][t][2];
    float sqr = sred[0][t][3] + sred[1][t][3];
    mxb[ns * 32768 + b * 1024 + o] = fmx;
    mnb[ns * 32768 + b * 1024 + o] = fmn;
    atomicAdd(&sum3[o], fmaf(1024.f, bo, smr));
    atomicAdd(&sq3[o],  fmaf(1024.f * bo, bo, fmaf(2.f * bo, smr, sqr)));
  }
}

// FC1 + pooled fused: pool slice derived inline from mxb/mnb/sum3/sq3 (BN3).
__global__ __launch_bounds__(256) void k_fc1(const float* __restrict__ mxb,
    const float* __restrict__ mnb, const float* __restrict__ sum3,
    const float* __restrict__ sq3, const float* __restrict__ g3,
    const float* __restrict__ be3, const float* __restrict__ wf1,
    const float* __restrict__ bf1, float* __restrict__ f1r)
{
  __shared__ float ins[32 * 128];   // 16 KB
  __shared__ float bnA[128], bnS[128];
  int t = threadIdx.x;
  int f0 = blockIdx.x * 32;
  int k0 = blockIdx.y * 128;
  if (t < 128) {
    int c = k0 + t;
    float m = sum3[c] * (1.f / 65536.f);
    float v = fmaf(-m, m, sq3[c] * (1.f / 65536.f));
    float a = g3[c] * rsqrtf(v + EPSV);
    bnA[t] = a; bnS[t] = fmaf(-a, m, be3[c]);
  }
  __syncthreads();
  #pragma unroll
  for (int i = 0; i < 4; ++i) {
    int idx = i * 256 + t;
    int b = idx >> 5, k4 = idx & 31;
    float4 mxv = *(const float4*)(mxb + (size_t)b * 1024 + k0 + k4 * 4);
    float4 mx1 = *(const float4*)(mxb + 32768 + (size_t)b * 1024 + k0 + k4 * 4);
    float4 mnv = *(const float4*)(mnb + (size_t)b * 1024 + k0 + k4 * 4);
    float4 mn1 = *(const float4*)(mnb + 32768 + (size_t)b * 1024 + k0 + k4 * 4);
    float4 a = *(const float4*)&bnA[k4 * 4];
    float4 s = *(const float4*)&bnS[k4 * 4];
    float4 r;
    r.x = fmaf(a.x, (a.x >= 0.f ? fmaxf(mxv.x, mx1.x) : fminf(mnv.x, mn1.x)), s.x);
    r.y = fmaf(a.y, (a.y >= 0.f ? fmaxf(mxv.y, mx1.y) : fminf(mnv.y, mn1.y)), s.y);
    r.z = fmaf(a.z, (a.z >= 0.f ? fmaxf(mxv.z, mx1.z) : fminf(mnv.z, mn1.z)), s.z);
    r.w = fmaf(a.w, (a.w >= 0.f ? fmaxf(mxv.w, mx1.w) : fminf(mnv.w, mn1.w)), s.w);
    *(float4*)&ins[b * 128 + k4 * 4] = r;
  }
  __syncthreads();
  int f = t & 31, bq = t >> 5;
  int bl = bq * 4;
  const float4* wr = (const float4*)(wf1 + (size_t)(f0 + f) * 1024 + k0);
  float acc0 = 0.f, acc1 = 0.f, acc2 = 0.f, acc3 = 0.f;
  #pragma unroll 4
  for (int k4 = 0; k4 < 32; ++k4) {
    float4 wv = wr[k4];
    float4 i0 = *(const float4*)&ins[(bl + 0) * 128 + k4 * 4];
    float4 i1 = *(const float4*)&ins[(bl + 1) * 128 + k4 * 4];
    float4 i2 = *(const float4*)&ins[(bl + 2) * 128 + k4 * 4];
    float4 i3 = *(const float4*)&ins[(bl + 3) * 128 + k4 * 4];
    acc0 = fmaf(wv.x, i0.x, fmaf(wv.y, i0.y, fmaf(wv.z, i0.z, fmaf(wv.w, i0.w, acc0))));
    acc1 = fmaf(wv.x, i1.x, fmaf(wv.y, i1.y, fmaf(wv.z, i1.z, fmaf(wv.w, i1.w, acc1))));
    acc2 = fmaf(wv.x, i2.x, fmaf(wv.y, i2.y, fmaf(wv.z, i2.z, fmaf(wv.w, i2.w, acc2))));
    acc3 = fmaf(wv.x, i3.x, fmaf(wv.y, i3.y, fmaf(wv.z, i3.z, fmaf(wv.w, i3.w, acc3))));
  }
  float bs = (blockIdx.y == 0) ? bf1[f0 + f] : 0.f;
  atomicAdd(&f1r[(size_t)(bl + 0) * 512 + f0 + f], acc0 + bs);
  atomicAdd(&f1r[(size_t)(bl + 1) * 512 + f0 + f], acc1 + bs);
  atomicAdd(&f1r[(size_t)(bl + 2) * 512 + f0 + f], acc2 + bs);
  atomicAdd(&f1r[(size_t)(bl + 3) * 512 + f0 + f], acc3 + bs);
}

// FC2: BN1d(f1) stats inline per k-chunk; unroll capped at 4.
__global__ __launch_bounds__(256) void k_fc2(const float* __restrict__ f1r,
    const float* __restrict__ wf2, const float* __restrict__ bf2,
    const float* __restrict__ gf1, const float* __restrict__ bef1,
    float* __restrict__ f2r)
{
  __shared__ float ins[32 * 64];    // 8 KB
  __shared__ float bnA[64], bnS[64];
  int t = threadIdx.x;
  int f0 = blockIdx.x * 32;
  int k0 = blockIdx.y * 64;
  #pragma unroll
  for (int i = 0; i < 2; ++i) {
    int idx = i * 256 + t;
    int b = idx >> 4, k4 = idx & 15;
    *(float4*)&ins[b * 64 + k4 * 4] = *(const float4*)(f1r + (size_t)b * 512 + k0 + k4 * 4);
  }
  __syncthreads();
  if (t < 64) {
    float s = 0.f, q = 0.f;
    #pragma unroll
    for (int b = 0; b < 32; ++b) {
      float xx = ins[b * 64 + t];
      s += xx; q = fmaf(xx, xx, q);
    }
    float m = s * (1.f / 32.f);
    float v = fmaf(-m, m, q * (1.f / 32.f));
    float a = gf1[k0 + t] * rsqrtf(v + EPSV);
    bnA[t] = a; bnS[t] = fmaf(-a, m, bef1[k0 + t]);
  }
  __syncthreads();
  #pragma unroll
  for (int i = 0; i < 2; ++i) {
    int idx = i * 256 + t;
    int b = idx >> 4, k4 = idx & 15;
    float4 v = *(const float4*)&ins[b * 64 + k4 * 4];
    v.x = fmaxf(fmaf(bnA[k4*4+0], v.x, bnS[k4*4+0]), 0.f);
    v.y = fmaxf(fmaf(bnA[k4*4+1], v.y, bnS[k4*4+1]), 0.f);
    v.z = fmaxf(fmaf(bnA[k4*4+2], v.z, bnS[k4*4+2]), 0.f);
    v.w = fmaxf(fmaf(bnA[k4*4+3], v.w, bnS[k4*4+3]), 0.f);
    *(float4*)&ins[b * 64 + k4 * 4] = v;
  }
  __syncthreads();
  int f = t & 31, bq = t >> 5;
  int bl = bq * 4;
  const float4* wr = (const float4*)(wf2 + (size_t)(f0 + f) * 512 + k0);
  float acc0 = 0.f, acc1 = 0.f, acc2 = 0.f, acc3 = 0.f;
  #pragma unroll 4
  for (int k4 = 0; k4 < 16; ++k4) {
    float4 wv = wr[k4];
    float4 i0 = *(const float4*)&ins[(bl + 0) * 64 + k4 * 4];
    float4 i1 = *(const float4*)&ins[(bl + 1) * 64 + k4 * 4];
    float4 i2 = *(const float4*)&ins[(bl + 2) * 64 + k4 * 4];
    float4 i3 = *(const float4*)&ins[(bl + 3) * 64 + k4 * 4];
    acc0 = fmaf(wv.x, i0.x, fmaf(wv.y, i0.y, fmaf(wv.z, i0.z, fmaf(wv.w, i0.w, acc0))));
    acc1 = fmaf(wv.x, i1.x, fmaf(wv.y, i1.y, fmaf(wv.z, i1.z, fmaf(wv.w, i1.w, acc1))));
    acc2 = fmaf(wv.x, i2.x, fmaf(wv.y, i2.y, fmaf(wv.z, i2.z, fmaf(wv.w, i2.w, acc2))));
    acc3 = fmaf(wv.x, i3.x, fmaf(wv.y, i3.y, fmaf(wv.z, i3.z, fmaf(wv.w, i3.w, acc3))));
  }
  float bs = (blockIdx.y == 0) ? bf2[f0 + f] : 0.f;
  atomicAdd(&f2r[(size_t)(bl + 0) * 256 + f0 + f], acc0 + bs);
  atomicAdd(&f2r[(size_t)(bl + 1) * 256 + f0 + f], acc1 + bs);
  atomicAdd(&f2r[(size_t)(bl + 2) * 256 + f0 + f], acc2 + bs);
  atomicAdd(&f2r[(size_t)(bl + 3) * 256 + f0 + f], acc3 + bs);
}

// Head: BN-F2 stats inline; p = relu(BN(f2r)) @ wp.T + bp; Horn SO(3) -> [B,4,4].
__global__ __launch_bounds__(384) void k_head(const float* __restrict__ f2r,
    const float* __restrict__ gf2, const float* __restrict__ bef2,
    const float* __restrict__ wp, const float* __restrict__ bp,
    float* __restrict__ out)
{
  __shared__ float pS[32 * 12];
  __shared__ float bnf[256][2];
  int t = threadIdx.x;
  if (t < 256) {
    float s = 0.f, q = 0.f;
    #pragma unroll
    for (int b = 0; b < 32; ++b) {
      float xx = f2r[b * 256 + t];
      s += xx; q = fmaf(xx, xx, q);
    }
    float m = s * (1.f / 32.f);
    float v = fmaf(-m, m, q * (1.f / 32.f));
    float a = gf2[t] * rsqrtf(v + EPSV);
    bnf[t][0] = a; bnf[t][1] = fmaf(-a, m, bef2[t]);
  }
  __syncthreads();
  {
    int b = t / 12, j = t % 12;
    const float* w = wp + j * 256;
    const float* fr = f2r + b * 256;
    float acc = bp[j];
    #pragma unroll 8
    for (int c = 0; c < 256; ++c) {
      float h = fmaxf(fmaf(bnf[c][0], fr[c], bnf[c][1]), 0.f);
      acc = fmaf(w[c], h, acc);
    }
    pS[t] = acc;
  }
  __syncthreads();
  if (t < 32) {
    const float* p = &pS[t * 12];
    float m00=p[0],m01=p[1],m02=p[2],m10=p[3],m11=p[4],m12=p[5],m20=p[6],m21=p[7],m22=p[8];
    float P[4][4];
    P[0][0]=m00+m11+m22; P[0][1]=m21-m12;     P[0][2]=m02-m20;     P[0][3]=m10-m01;
    P[1][1]=m00-m11-m22; P[1][2]=m01+m10;     P[1][3]=m02+m20;
    P[2][2]=m11-m00-m22; P[2][3]=m12+m21;
    P[3][3]=m22-m00-m11;
    P[1][0]=P[0][1]; P[2][0]=P[0][2]; P[3][0]=P[0][3];
    P[2][1]=P[1][2]; P[3][1]=P[1][3]; P[3][2]=P[2][3];
    float fn = sqrtf(m00*m00+m01*m01+m02*m02+m10*m10+m11*m11+m12*m12+m20*m20+m21*m21+m22*m22);
    float inv = 1.f / (2.f * fn + 1e-30f);
    #pragma unroll
    for (int i = 0; i < 4; ++i)
      #pragma unroll
      for (int j = 0; j < 4; ++j) P[i][j] *= inv;
    P[0][0] += 1.f; P[1][1] += 1.f; P[2][2] += 1.f; P[3][3] += 1.f;
    for (int it = 0; it < 16; ++it) {
      float Q[4][4];
      #pragma unroll
      for (int i = 0; i < 4; ++i)
        #pragma unroll
        for (int j = 0; j < 4; ++j)
          Q[i][j] = P[i][0]*P[0][j] + P[i][1]*P[1][j] + P[i][2]*P[2][j] + P[i][3]*P[3][j];
      float mxa = 0.f;
      #pragma unroll
      for (int i = 0; i < 4; ++i)
        #pragma unroll
        for (int j = 0; j < 4; ++j) mxa = fmaxf(mxa, fabsf(Q[i][j]));
      float r = 1.f / mxa;
      #pragma unroll
      for (int i = 0; i < 4; ++i)
        #pragma unroll
        for (int j = 0; j < 4; ++j) P[i][j] = Q[i][j] * r;
    }
    float bestn = -1.f; int bj = 0;
    #pragma unroll
    for (int j = 0; j < 4; ++j) {
      float nn = P[0][j]*P[0][j] + P[1][j]*P[1][j] + P[2][j]*P[2][j] + P[3][j]*P[3][j];
      if (nn > bestn) { bestn = nn; bj = j; }
    }
    float qw = P[0][bj], qx = P[1][bj], qy = P[2][bj], qz = P[3][bj];
    float qn = rsqrtf(qw*qw + qx*qx + qy*qy + qz*qz);
    qw *= qn; qx *= qn; qy *= qn; qz *= qn;
    float* ob = out + t * 16;
    ob[0]  = 1.f - 2.f*(qy*qy + qz*qz);
    ob[1]  = 2.f*(qx*qy - qw*qz);
    ob[2]  = 2.f*(qx*qz + qw*qy);
    ob[3]  = p[9];
    ob[4]  = 2.f*(qx*qy + qw*qz);
    ob[5]  = 1.f - 2.f*(qx*qx + qz*qz);
    ob[6]  = 2.f*(qy*qz - qw*qx);
    ob[7]  = p[10];
    ob[8]  = 2.f*(qx*qz - qw*qy);
    ob[9]  = 2.f*(qy*qz + qw*qx);
    ob[10] = 1.f - 2.f*(qx*qx + qy*qy);
    ob[11] = p[11];
    ob[12] = 0.f; ob[13] = 0.f; ob[14] = 0.f; ob[15] = 1.f;
  }
}

extern "C" void kernel_launch(void* const* d_in, const int* in_sizes, int n_in,
                              void* d_out, int out_size, void* d_ws, size_t ws_size,
                              hipStream_t stream)
{
  (void)in_sizes; (void)n_in; (void)out_size;
  if (ws_size < (size_t)WS_FLOATS * sizeof(float)) return;
  const float* x   = (const float*)d_in[0];
  const float* w1  = (const float*)d_in[1];
  const float* b1  = (const float*)d_in[2];
  const float* g1  = (const float*)d_in[3];
  const float* be1 = (const float*)d_in[4];
  const float* w2  = (const float*)d_in[5];
  const float* b2  = (const float*)d_in[6];
  const float* g2  = (const float*)d_in[7];
  const float* be2 = (const float*)d_in[8];
  const float* w3  = (const float*)d_in[9];
  const float* b3  = (const float*)d_in[10];
  const float* g3  = (const float*)d_in[11];
  const float* be3 = (const float*)d_in[12];
  const float* wf1 = (const float*)d_in[13];
  const float* bf1 = (const float*)d_in[14];
  const float* gf1 = (const float*)d_in[15];
  const float* bef1= (const float*)d_in[16];
  const float* wf2 = (const float*)d_in[17];
  const float* bf2 = (const float*)d_in[18];
  const float* gf2 = (const float*)d_in[19];
  const float* bef2= (const float*)d_in[20];
  const float* wp  = (const float*)d_in[21];
  const float* bp  = (const float*)d_in[22];
  float* ws  = (float*)d_ws;
  float* out = (float*)d_out;
  unsigned short* y2t = (unsigned short*)(ws + OFF_Y2T);
  unsigned short* h2t = (unsigned short*)(ws + OFF_H2T);
  unsigned short* w3h = (unsigned short*)(ws + OFF_W3H);
  unsigned short* w2h = (unsigned short*)(ws + OFF_W2H);

  hipMemsetAsync((void*)(ws + OFF_Z), 0, ZN * sizeof(float), stream);
  k_prep<<<200, 256, 0, stream>>>(w3, w2, w3h, w2h, x, ws + OFF_XS);
  k_conv12<<<1024, 256, 0, stream>>>(x, w1, b1, g1, be1, ws + OFF_XS,
                                     w2h, b2, y2t, ws + OFF_SUM2, ws + OFF_SQ2);
  k_bnrelu2<<<1024, 256, 0, stream>>>(y2t, ws + OFF_SUM2, ws + OFF_SQ2, g2, be2, h2t);
  k_conv3<<<512, 256, 0, stream>>>(h2t, w3h, b3, ws + OFF_MX, ws + OFF_MN,
                                   ws + OFF_SUM3, ws + OFF_SQ3);
  k_fc1<<<dim3(16, 8), 256, 0, stream>>>(ws + OFF_MX, ws + OFF_MN, ws + OFF_SUM3,
                                         ws + OFF_SQ3, g3, be3, wf1, bf1, ws + OFF_F1R);
  k_fc2<<<dim3(8, 8), 256, 0, stream>>>(ws + OFF_F1R, wf2, bf2, gf1, bef1, ws + OFF_F2R);
  k_head<<<1, 384, 0, stream>>>(ws + OFF_F2R, gf2, bef2, wp, bp, out);
}